// Round 3
// baseline (1075.300 us; speedup 1.0000x reference)
//
#include <hip/hip_runtime.h>
#include <stdint.h>
#include <stddef.h>

// GINE layer, MI355X -- round 7.
// R6 post-mortem: halving edge VMEM instrs changed nothing (137.7us, 45% BW,
// occ 30%) -> not issue-limited; occupancy capped by VGPR+AGPR (~148/wave ->
// 3 waves/SIMD). Bigger finding: total 611us but edge only 137 -> ~474us in
// the other kernels; the msg round-trip (200MB write + 205MB read + reduce
// kernel) is ~65% of pipeline HBM traffic and purely structural.
// R7: FUSE edge+reduce. Edges sorted by dst (basep/cursor exist); each wave
// owns 8 dst nodes + their contiguous sorted-edge range. Per 16-edge chunk:
// gather ea rows via eorg, x via esrc, MFMA as before, accumulate relu'd f32
// messages into per-wave LDS rows (9 x 132 padded; row 8 = scratch absorbing
// chunk padding via boundary-count). Epilogue adds (1+eps)*x, writes hbf.
// Eliminates msg (410MB), reduce_kernel, pos array. f32 accumulation (no
// intermediate bf16 rounding) -> accuracy improves.

#define NN 50000
#define EE 800000
#define DD 128
#define DE 64
#define H1 256
#define NGRP 3125   // NN/16 exactly
#define NPW 8       // dst nodes per wave
#define LROW 132    // padded floats per accumulator row (528B, 16B-aligned)
#define NROW 9      // 8 real + 1 scratch

typedef __attribute__((ext_vector_type(8))) short short8;
typedef __attribute__((ext_vector_type(4))) float floatx4;

__device__ __forceinline__ short f2bf(float f) {
    union { float f; uint32_t u; } v; v.f = f;
    return (short)((v.u + 0x7FFFu + ((v.u >> 16) & 1u)) >> 16);  // RNE
}
__device__ __forceinline__ float bf2f(uint16_t u) {
    union { uint32_t u; float f; } v; v.u = (uint32_t)u << 16;
    return v.f;
}

// ---- merged weight swizzle: We(8192) + W1(32768) + W2(32768) items
// We's OUTPUT feature mapping: MFMA col (nt, l16) holds feature l16*8 + nt
// (per-lane x/be/acc slices contiguous). W1/W2 natural n = nt*16 + l16.
__global__ __launch_bounds__(256) void swz_all_kernel(
    const float* __restrict__ We, const float* __restrict__ W1,
    const float* __restrict__ W2, short* __restrict__ dst) {
    int idx = blockIdx.x * 256 + threadIdx.x;
    if (idx >= 73728) return;
    const float* src; int KC, K, local; short* dp; bool efeat = false;
    if (idx < 8192)       { src = We; KC = 2; K = 64;  local = idx;          dp = dst; efeat = true; }
    else if (idx < 40960) { src = W1; KC = 4; K = 128; local = idx - 8192;  dp = dst + 8192; }
    else                  { src = W2; KC = 8; K = 256; local = idx - 40960; dp = dst + 40960; }
    int j = local & 7;
    int lane = (local >> 3) & 63;
    int f = local >> 9;
    int kc = f % KC;
    int nt = f / KC;
    int n = efeat ? ((lane & 15) * 8 + nt) : (nt * 16 + (lane & 15));
    int k = kc * 32 + ((lane >> 4) & 3) * 8 + j;
    dp[local] = f2bf(src[(size_t)n * K + k]);
}

// ---- sort-by-dst machinery ----
__global__ __launch_bounds__(256) void count_kernel(const int* __restrict__ ei,
                                                    uint32_t* __restrict__ deg) {
    int e = blockIdx.x * 256 + threadIdx.x;
    atomicAdd(&deg[ei[EE + e]], 1u);
}

__global__ __launch_bounds__(256) void scan1_kernel(const uint32_t* __restrict__ deg,
                                                    uint32_t* __restrict__ partial) {
    __shared__ uint32_t ls[256];
    int i = blockIdx.x * 256 + threadIdx.x;
    ls[threadIdx.x] = deg[i];
    __syncthreads();
    for (int s = 128; s > 0; s >>= 1) {
        if (threadIdx.x < s) ls[threadIdx.x] += ls[threadIdx.x + s];
        __syncthreads();
    }
    if (threadIdx.x == 0) partial[blockIdx.x] = ls[0];
}

__global__ __launch_bounds__(256) void scan2_kernel(uint32_t* __restrict__ partial) {
    __shared__ uint32_t ls[196];
    if (threadIdx.x < 196) ls[threadIdx.x] = partial[threadIdx.x];
    __syncthreads();
    if (threadIdx.x == 0) {
        uint32_t run = 0;
        for (int i = 0; i < 196; ++i) { uint32_t t = ls[i]; ls[i] = run; run += t; }
    }
    __syncthreads();
    if (threadIdx.x < 196) partial[threadIdx.x] = ls[threadIdx.x];
}

__global__ __launch_bounds__(256) void scan3_kernel(const uint32_t* __restrict__ deg,
                                                    const uint32_t* __restrict__ partial,
                                                    uint32_t* __restrict__ base,
                                                    uint32_t* __restrict__ cursor) {
    __shared__ uint32_t ls[256];
    int i = blockIdx.x * 256 + threadIdx.x;
    uint32_t v = (i < NN) ? deg[i] : 0u;
    ls[threadIdx.x] = v;
    __syncthreads();
    for (int off = 1; off < 256; off <<= 1) {
        uint32_t t = (threadIdx.x >= off) ? ls[threadIdx.x - off] : 0u;
        __syncthreads();
        ls[threadIdx.x] += t;
        __syncthreads();
    }
    if (i < NN) {
        uint32_t b = partial[blockIdx.x] + ls[threadIdx.x] - v;  // exclusive
        base[i] = b;
        cursor[i] = b;
    } else if (i == NN) {
        base[NN] = EE;
    }
}

// scatter (src, orig-id) into sorted-by-dst slots
__global__ __launch_bounds__(256) void scat_kernel(const int* __restrict__ ei,
                                                   uint32_t* __restrict__ cursor,
                                                   int* __restrict__ esrc,
                                                   uint32_t* __restrict__ eorg) {
    int e = blockIdx.x * 256 + threadIdx.x;
    uint32_t p = atomicAdd(&cursor[ei[EE + e]], 1u);
    esrc[p] = ei[e];
    eorg[p] = (uint32_t)e;
}

// ---- fused edge+reduce: per wave, 8 dst nodes; walk sorted edge range in
// 16-edge MFMA chunks; accumulate relu(x_src + ea@We^T + be) into LDS rows;
// epilogue h[n] = (1+eps)*x[n] + acc -> hbf (bf16).
__global__ __launch_bounds__(256) void fused_kernel(
    const float* __restrict__ x,
    const uint32_t* __restrict__ basep,
    const int* __restrict__ esrc,
    const uint32_t* __restrict__ eorg,
    const float* __restrict__ ea,
    const short* __restrict__ weswz,
    const float* __restrict__ be,
    const float* __restrict__ epsp,
    uint16_t* __restrict__ hbf)
{
    __shared__ float lacc[4][NROW * LROW];
    const int wave = threadIdx.x >> 6;
    const int lane = threadIdx.x & 63;
    const int l16 = lane & 15;
    const int q = lane >> 4;
    float* my = lacc[wave];

    const int wid = blockIdx.x * 4 + wave;
    const int n0 = wid * NPW;
    if (n0 >= NN) return;

    // zero accumulator rows (wave-private)
#pragma unroll
    for (int k = 0; k < NROW * LROW; k += 64) {
        int kk = k + lane;
        if (kk < NROW * LROW) my[kk] = 0.f;
    }

    const short8* wp = (const short8*)weswz;
    short8 bfr[16];
#pragma unroll
    for (int f = 0; f < 16; ++f) bfr[f] = wp[f * 64 + lane];
    floatx4 bv0 = *(const floatx4*)(be + l16 * 8);
    floatx4 bv1 = *(const floatx4*)(be + l16 * 8 + 4);

    uint32_t bpk[NPW + 1];
#pragma unroll
    for (int k = 0; k <= NPW; ++k) {
        int nk = n0 + k; if (nk > NN) nk = NN;
        bpk[k] = basep[nk];
    }
    const uint32_t eb = bpk[0], ee2 = bpk[NPW];

    __asm__ volatile("s_waitcnt lgkmcnt(0)" ::: "memory");  // zeros committed

    // prefetch first chunk's index data
    uint32_t org = eorg[min(eb + (uint32_t)l16, (uint32_t)(EE - 1))];
    int srcv[4];
#pragma unroll
    for (int r = 0; r < 4; ++r)
        srcv[r] = esrc[min(eb + (uint32_t)(q * 4 + r), (uint32_t)(EE - 1))];

    for (uint32_t i = eb; i < ee2; i += 16) {
        // gather ea row pieces (chunk-edge l16, k-slice q)
        const float* earow = ea + (size_t)org * DE + q * 8;
        floatx4 p0 = *(const floatx4*)(earow);
        floatx4 p1 = *(const floatx4*)(earow + 4);
        floatx4 p2 = *(const floatx4*)(earow + 32);
        floatx4 p3 = *(const floatx4*)(earow + 36);
        // gather x rows (chunk-edges q*4+r)
        floatx4 xa[4], xb[4];
#pragma unroll
        for (int r = 0; r < 4; ++r) {
            const float* xr = x + (size_t)srcv[r] * DD + l16 * 8;
            xa[r] = *(const floatx4*)(xr);
            xb[r] = *(const floatx4*)(xr + 4);
        }
        // prefetch next chunk's index data
        uint32_t orgN = org; int srcN[4];
#pragma unroll
        for (int r = 0; r < 4; ++r) srcN[r] = srcv[r];
        if (i + 16 < ee2) {
            orgN = eorg[min(i + 16u + (uint32_t)l16, (uint32_t)(EE - 1))];
#pragma unroll
            for (int r = 0; r < 4; ++r)
                srcN[r] = esrc[min(i + 16u + (uint32_t)(q * 4 + r), (uint32_t)(EE - 1))];
        }
        short8 af0, af1;
#pragma unroll
        for (int j = 0; j < 4; ++j) {
            af0[j]     = f2bf(p0[j]);
            af0[j + 4] = f2bf(p1[j]);
            af1[j]     = f2bf(p2[j]);
            af1[j + 4] = f2bf(p3[j]);
        }
        floatx4 acc[8];
#pragma unroll
        for (int t = 0; t < 8; ++t) {
            floatx4 z = {0.f, 0.f, 0.f, 0.f};
            z = __builtin_amdgcn_mfma_f32_16x16x32_bf16(af0, bfr[t * 2], z, 0, 0, 0);
            acc[t] = __builtin_amdgcn_mfma_f32_16x16x32_bf16(af1, bfr[t * 2 + 1], z, 0, 0, 0);
        }
        // accumulate into LDS rows; out-of-range edges land in scratch row 8
#pragma unroll
        for (int r = 0; r < 4; ++r) {
            const uint32_t idx = i + (uint32_t)(q * 4 + r);
            int nl = 0;
#pragma unroll
            for (int k = 1; k <= NPW; ++k) nl += (idx >= bpk[k]) ? 1 : 0;
            float* bl = my + nl * LROW + l16 * 8;
#pragma unroll
            for (int t = 0; t < 8; ++t) {
                float xv = (t < 4) ? xa[r][t] : xb[r][t - 4];
                float bvv = (t < 4) ? bv0[t] : bv1[t - 4];
                float v = fmaxf(acc[t][r] + bvv + xv, 0.f);
                atomicAdd(bl + t, v);
            }
        }
        org = orgN;
#pragma unroll
        for (int r = 0; r < 4; ++r) srcv[r] = srcN[r];
    }

    __asm__ volatile("s_waitcnt lgkmcnt(0)" ::: "memory");  // adds committed
    // epilogue: lane = nl*8 + s; 16 features per lane
    const int nl = lane >> 3;
    const int s = lane & 7;
    const int n = n0 + nl;
    if (n < NN) {
        const float c1 = 1.0f + epsp[0];
        const float* ar = my + nl * LROW + s * 16;
        const float* xr = x + (size_t)n * DD + s * 16;
        uint32_t pk[8];
#pragma unroll
        for (int w = 0; w < 4; ++w) {
            floatx4 av = *(const floatx4*)(ar + w * 4);
            floatx4 xv = *(const floatx4*)(xr + w * 4);
            pk[w * 2]     = (uint32_t)(uint16_t)f2bf(c1 * xv[0] + av[0]) |
                            ((uint32_t)(uint16_t)f2bf(c1 * xv[1] + av[1]) << 16);
            pk[w * 2 + 1] = (uint32_t)(uint16_t)f2bf(c1 * xv[2] + av[2]) |
                            ((uint32_t)(uint16_t)f2bf(c1 * xv[3] + av[3]) << 16);
        }
        uint16_t* op = hbf + (size_t)n * DD + s * 16;
        *(uint4*)(op)     = (uint4){pk[0], pk[1], pk[2], pk[3]};
        *(uint4*)(op + 8) = (uint4){pk[4], pk[5], pk[6], pk[7]};
    }
}

// ---- GEMM1: t1[N,256](bf16) = h @ W1^T + b1, fused BN1 stats
__global__ __launch_bounds__(256) void gemm1_kernel(
    const uint16_t* __restrict__ hbf,
    const short* __restrict__ w1swz,
    const float* __restrict__ b1,
    uint16_t* __restrict__ t1,
    float* __restrict__ gsum,
    float* __restrict__ gsq)
{
    __shared__ float ls[H1];
    __shared__ float ls2[H1];
    const int tid = threadIdx.x;
    ls[tid] = 0.f; ls2[tid] = 0.f;
    __syncthreads();

    const int wave = tid >> 6;
    const int lane = tid & 63;
    const int l16 = lane & 15;
    const int q = lane >> 4;
    const short8* wp = (const short8*)w1swz;

    const int grp = blockIdx.x * 4 + wave;
    if (grp < NGRP) {
        const int n0 = grp * 16;
        const uint16_t* hr = hbf + (size_t)(n0 + l16) * DD + q * 8;
        short8 af[4];
#pragma unroll
        for (int kc = 0; kc < 4; ++kc) af[kc] = *(const short8*)(hr + kc * 32);
#pragma unroll
        for (int nt = 0; nt < 16; ++nt) {
            floatx4 acc = {0.f, 0.f, 0.f, 0.f};
#pragma unroll
            for (int kc = 0; kc < 4; ++kc)
                acc = __builtin_amdgcn_mfma_f32_16x16x32_bf16(
                    af[kc], wp[(nt * 4 + kc) * 64 + lane], acc, 0, 0, 0);
            const float bb = b1[nt * 16 + l16];
            float s = 0.f, s2 = 0.f;
#pragma unroll
            for (int r = 0; r < 4; ++r) {
                float v = acc[r] + bb;
                t1[(size_t)(n0 + q * 4 + r) * H1 + nt * 16 + l16] = (uint16_t)f2bf(v);
                s += v; s2 += v * v;
            }
            atomicAdd(&ls[nt * 16 + l16], s);
            atomicAdd(&ls2[nt * 16 + l16], s2);
        }
    }
    __syncthreads();
    atomicAdd(&gsum[tid], ls[tid]);
    atomicAdd(&gsq[tid], ls2[tid]);
}

// ---- GEMM2: h2[N,128](bf16) = relu(t1*scale1+shift1) @ W2^T + b2, BN2 stats
__global__ __launch_bounds__(256) void gemm2_kernel(
    const uint16_t* __restrict__ t1,
    const float* __restrict__ scale1,
    const float* __restrict__ shift1,
    const short* __restrict__ w2swz,
    const float* __restrict__ b2,
    uint16_t* __restrict__ h2,
    float* __restrict__ gsum,
    float* __restrict__ gsq)
{
    __shared__ float ls[DD];
    __shared__ float ls2[DD];
    const int tid = threadIdx.x;
    if (tid < DD) { ls[tid] = 0.f; ls2[tid] = 0.f; }
    __syncthreads();

    const int wave = tid >> 6;
    const int lane = tid & 63;
    const int l16 = lane & 15;
    const int q = lane >> 4;
    const short8* wp = (const short8*)w2swz;

    const int grp = blockIdx.x * 4 + wave;
    if (grp < NGRP) {
        const int n0 = grp * 16;
        const uint16_t* tr = t1 + (size_t)(n0 + l16) * H1 + q * 8;
        floatx4 acc[8];
#pragma unroll
        for (int nt = 0; nt < 8; ++nt) acc[nt] = (floatx4){0.f, 0.f, 0.f, 0.f};
#pragma unroll
        for (int kc = 0; kc < 8; ++kc) {
            short8 tv = *(const short8*)(tr + kc * 32);
            const int kb = kc * 32 + q * 8;
            short8 af;
#pragma unroll
            for (int j = 0; j < 8; ++j) {
                float u = bf2f((uint16_t)tv[j]) * scale1[kb + j] + shift1[kb + j];
                af[j] = f2bf(fmaxf(u, 0.f));
            }
#pragma unroll
            for (int nt = 0; nt < 8; ++nt)
                acc[nt] = __builtin_amdgcn_mfma_f32_16x16x32_bf16(
                    af, wp[(nt * 8 + kc) * 64 + lane], acc[nt], 0, 0, 0);
        }
#pragma unroll
        for (int nt = 0; nt < 8; ++nt) {
            const float bb = b2[nt * 16 + l16];
            float s = 0.f, s2 = 0.f;
#pragma unroll
            for (int r = 0; r < 4; ++r) {
                float v = acc[nt][r] + bb;
                h2[(size_t)(n0 + q * 4 + r) * DD + nt * 16 + l16] = (uint16_t)f2bf(v);
                s += v; s2 += v * v;
            }
            atomicAdd(&ls[nt * 16 + l16], s);
            atomicAdd(&ls2[nt * 16 + l16], s2);
        }
    }
    __syncthreads();
    if (tid < DD) {
        atomicAdd(&gsum[tid], ls[tid]);
        atomicAdd(&gsq[tid], ls2[tid]);
    }
}

__global__ void finalize_kernel(const float* __restrict__ ssum,
                                const float* __restrict__ ssumsq,
                                const float* __restrict__ gamma,
                                const float* __restrict__ beta,
                                float* __restrict__ scale,
                                float* __restrict__ shift, int C) {
    int c = threadIdx.x;
    if (c >= C) return;
    float mu = ssum[c] * (1.0f / NN);
    float var = ssumsq[c] * (1.0f / NN) - mu * mu;
    float rs = rsqrtf(var + 1e-5f);
    float sc = gamma[c] * rs;
    scale[c] = sc;
    shift[c] = beta[c] - mu * sc;
}

__global__ __launch_bounds__(256) void out_kernel(const uint16_t* __restrict__ h2,
                                                  const float* __restrict__ scale2,
                                                  const float* __restrict__ shift2,
                                                  float* __restrict__ out) {
    int idx = blockIdx.x * 256 + threadIdx.x;
    int base = idx * 8;   // NN*DD = 6.4M elems, 800000 threads
    int c = base & (DD - 1);
    uint4 pk = *(const uint4*)(h2 + base);
    const uint32_t u[4] = {pk.x, pk.y, pk.z, pk.w};
    floatx4 o0, o1;
#pragma unroll
    for (int j = 0; j < 4; ++j) {
        float vlo = bf2f((uint16_t)(u[j] & 0xFFFFu));
        float vhi = bf2f((uint16_t)(u[j] >> 16));
        int cc = c + j * 2;
        float a = fmaxf(vlo * scale2[cc] + shift2[cc], 0.f);
        float b = fmaxf(vhi * scale2[cc + 1] + shift2[cc + 1], 0.f);
        if (j < 2) { o0[j * 2] = a; o0[j * 2 + 1] = b; }
        else       { o1[(j - 2) * 2] = a; o1[(j - 2) * 2 + 1] = b; }
    }
    *(floatx4*)(out + base) = o0;
    *(floatx4*)(out + base + 4) = o1;
}

extern "C" void kernel_launch(void* const* d_in, const int* in_sizes, int n_in,
                              void* d_out, int out_size, void* d_ws, size_t ws_size,
                              hipStream_t stream) {
    const float* x     = (const float*)d_in[0];
    const int*   ei    = (const int*)d_in[1];
    const float* ea    = (const float*)d_in[2];
    const float* We    = (const float*)d_in[3];
    const float* be    = (const float*)d_in[4];
    const float* W1    = (const float*)d_in[5];
    const float* b1    = (const float*)d_in[6];
    const float* g1    = (const float*)d_in[7];
    const float* beta1 = (const float*)d_in[8];
    const float* W2    = (const float*)d_in[9];
    const float* b2    = (const float*)d_in[10];
    const float* g2    = (const float*)d_in[11];
    const float* beta2 = (const float*)d_in[12];
    const float* epsp  = (const float*)d_in[13];

    float* ws      = (float*)d_ws;
    float* gsum1   = ws + 0;
    float* gsq1    = ws + 256;
    float* gsum2   = ws + 512;
    float* gsq2    = ws + 640;
    float* scale1  = ws + 768;
    float* shift1  = ws + 1024;
    float* scale2  = ws + 1280;
    float* shift2  = ws + 1408;
    uint32_t* deg     = (uint32_t*)(ws + 1536);   // 50176
    uint32_t* basep   = deg + 50176;              // 50432 (NN+1 used)
    uint32_t* cursor  = basep + 50432;            // 50176
    uint32_t* partial = cursor + 50176;           // 256
    int*      esrc    = (int*)(partial + 256);    // 800000
    uint32_t* eorg    = (uint32_t*)(esrc + EE);   // 800000
    uint16_t* hbf     = (uint16_t*)(eorg + EE);   // NN*DD
    uint16_t* t1      = hbf + (size_t)NN * DD;    // NN*H1
    uint16_t* h2      = t1 + (size_t)NN * H1;     // NN*DD
    short*    wswz    = (short*)(h2 + (size_t)NN * DD);  // 73728
    short*    weswz   = wswz;
    short*    w1swz   = wswz + 8192;
    short*    w2swz   = wswz + 40960;

    // zero stats (1536 f32) + deg (50176 u32), contiguous
    hipMemsetAsync(ws, 0, (1536 + 50176) * sizeof(uint32_t), stream);

    swz_all_kernel<<<dim3(288), 256, 0, stream>>>(We, W1, W2, wswz);
    count_kernel<<<dim3(3125), 256, 0, stream>>>(ei, deg);
    scan1_kernel<<<dim3(196), 256, 0, stream>>>(deg, partial);
    scan2_kernel<<<dim3(1), 256, 0, stream>>>(partial);
    scan3_kernel<<<dim3(196), 256, 0, stream>>>(deg, partial, basep, cursor);
    scat_kernel<<<dim3(3125), 256, 0, stream>>>(ei, cursor, esrc, eorg);

    fused_kernel<<<dim3(1563), 256, 0, stream>>>(x, basep, esrc, eorg, ea,
                                                 weswz, be, epsp, hbf);

    gemm1_kernel<<<dim3(782), 256, 0, stream>>>(hbf, w1swz, b1, t1, gsum1, gsq1);
    finalize_kernel<<<dim3(1), 256, 0, stream>>>(gsum1, gsq1, g1, beta1, scale1, shift1, H1);

    gemm2_kernel<<<dim3(782), 256, 0, stream>>>(t1, scale1, shift1, w2swz, b2, h2, gsum2, gsq2);
    finalize_kernel<<<dim3(1), 128, 0, stream>>>(gsum2, gsq2, g2, beta2, scale2, shift2, DD);

    out_kernel<<<dim3(3125), 256, 0, stream>>>(h2, scale2, shift2, (float*)d_out);
}

// Round 6
// 572.491 us; speedup vs baseline: 1.8783x; 1.8783x over previous
//
#include <hip/hip_runtime.h>
#include <stdint.h>
#include <stddef.h>

// GINE layer, MI355X -- round 10.
// R9 post-mortem: folding pos into edge had ALL 16 l16-lanes atomicAdd-claim
// the same 4 edges (16x over-claim) -> 16 lanes of one msg row scattered to
// 16 different rows + cursor overran segments + OOB stores corrupted the
// weight buffer after msg (absmax 9.8). R6's pos[e] was a READ (dup-safe);
// a CLAIM is not.
// R10: claim each edge once (lanes 0..15 claim e0+lane), broadcast slot via
// __shfl(claim, q*4+r). Keeps R9's verified-by-inspection tail changes:
//  (a) efeat W1/W2 swizzle -> t1 stored as 8 dwordx4 (was 64 scalar 2B),
//      h2 as 4 dwordx4 (was 32); outputs in natural order.
//  (b) BN stats reduced over q via shfl_xor(16/32), single LDS atomic from
//      q==0 (was 4-way same-address collision).
//  (c) pos_kernel eliminated (one fewer 800k-edge pass + launch).

#define NN 50000
#define EE 800000
#define DD 128
#define DE 64
#define H1 256
#define NGRP 3125   // NN/16 exactly

typedef __attribute__((ext_vector_type(8))) short short8;
typedef __attribute__((ext_vector_type(4))) float floatx4;

__device__ __forceinline__ short f2bf(float f) {
    union { float f; uint32_t u; } v; v.f = f;
    return (short)((v.u + 0x7FFFu + ((v.u >> 16) & 1u)) >> 16);  // RNE
}
__device__ __forceinline__ float bf2f(uint16_t u) {
    union { uint32_t u; float f; } v; v.u = (uint32_t)u << 16;
    return v.f;
}

// ---- merged weight swizzle: We(8192) + W1(32768) + W2(32768) items
// efeat mapping everywhere: MFMA col (nt, l16) holds orig feature
// l16*NTILES + nt  (We: NTILES=8, W1: 16, W2: 8). Lane-held outputs become
// natural-contiguous; K axes natural.
__global__ __launch_bounds__(256) void swz_all_kernel(
    const float* __restrict__ We, const float* __restrict__ W1,
    const float* __restrict__ W2, short* __restrict__ dst) {
    int idx = blockIdx.x * 256 + threadIdx.x;
    if (idx >= 73728) return;
    const float* src; int KC, K, NT, local; short* dp;
    if (idx < 8192)       { src = We; KC = 2; K = 64;  NT = 8;  local = idx;          dp = dst; }
    else if (idx < 40960) { src = W1; KC = 4; K = 128; NT = 16; local = idx - 8192;  dp = dst + 8192; }
    else                  { src = W2; KC = 8; K = 256; NT = 8;  local = idx - 40960; dp = dst + 40960; }
    int j = local & 7;
    int lane = (local >> 3) & 63;
    int f = local >> 9;
    int kc = f % KC;
    int nt = f / KC;
    int n = (lane & 15) * NT + nt;
    int k = kc * 32 + ((lane >> 4) & 3) * 8 + j;
    dp[local] = f2bf(src[(size_t)n * K + k]);
}

// ---- sort-by-dst machinery ----
__global__ __launch_bounds__(256) void count_kernel(const int* __restrict__ ei,
                                                    uint32_t* __restrict__ deg) {
    int e = blockIdx.x * 256 + threadIdx.x;
    atomicAdd(&deg[ei[EE + e]], 1u);
}

__global__ __launch_bounds__(256) void scan1_kernel(const uint32_t* __restrict__ deg,
                                                    uint32_t* __restrict__ partial) {
    __shared__ uint32_t ls[256];
    int i = blockIdx.x * 256 + threadIdx.x;
    ls[threadIdx.x] = deg[i];
    __syncthreads();
    for (int s = 128; s > 0; s >>= 1) {
        if (threadIdx.x < s) ls[threadIdx.x] += ls[threadIdx.x + s];
        __syncthreads();
    }
    if (threadIdx.x == 0) partial[blockIdx.x] = ls[0];
}

__global__ __launch_bounds__(256) void scan2_kernel(uint32_t* __restrict__ partial) {
    __shared__ uint32_t ls[196];
    if (threadIdx.x < 196) ls[threadIdx.x] = partial[threadIdx.x];
    __syncthreads();
    if (threadIdx.x == 0) {
        uint32_t run = 0;
        for (int i = 0; i < 196; ++i) { uint32_t t = ls[i]; ls[i] = run; run += t; }
    }
    __syncthreads();
    if (threadIdx.x < 196) partial[threadIdx.x] = ls[threadIdx.x];
}

__global__ __launch_bounds__(256) void scan3_kernel(const uint32_t* __restrict__ deg,
                                                    const uint32_t* __restrict__ partial,
                                                    uint32_t* __restrict__ base,
                                                    uint32_t* __restrict__ cursor) {
    __shared__ uint32_t ls[256];
    int i = blockIdx.x * 256 + threadIdx.x;
    uint32_t v = (i < NN) ? deg[i] : 0u;
    ls[threadIdx.x] = v;
    __syncthreads();
    for (int off = 1; off < 256; off <<= 1) {
        uint32_t t = (threadIdx.x >= off) ? ls[threadIdx.x - off] : 0u;
        __syncthreads();
        ls[threadIdx.x] += t;
        __syncthreads();
    }
    if (i < NN) {
        uint32_t b = partial[blockIdx.x] + ls[threadIdx.x] - v;  // exclusive
        base[i] = b;
        cursor[i] = b;
    } else if (i == NN) {
        base[NN] = EE;
    }
}

// ---- edge kernel: msg_row[claimed slot of dst] = bf16(relu(x[src]+ea@We^T+be))
// Each edge claimed ONCE (lanes 0..15 claim e0+lane), slot broadcast via
// __shfl. efeat We mapping keeps per-lane x/be/store slices contiguous;
// msg rows in NATURAL feature order.
#define EDGE_GPW 5
__global__ __launch_bounds__(256) void edge_kernel(
    const float* __restrict__ x,
    const int* __restrict__ ei,
    const float* __restrict__ ea,
    const short* __restrict__ weswz,
    const float* __restrict__ be,
    uint32_t* __restrict__ cursor,
    uint16_t* __restrict__ msg)
{
    const int wave = threadIdx.x >> 6;
    const int lane = threadIdx.x & 63;
    const int l16 = lane & 15;
    const int q = lane >> 4;

    const short8* wp = (const short8*)weswz;
    short8 bfr[16];
#pragma unroll
    for (int f = 0; f < 16; ++f) bfr[f] = wp[f * 64 + lane];
    floatx4 bv0 = *(const floatx4*)(be + l16 * 8);
    floatx4 bv1 = *(const floatx4*)(be + l16 * 8 + 4);

    const int gbase = (blockIdx.x * 4 + wave) * EDGE_GPW;
    int sidx[4];
#pragma unroll
    for (int r = 0; r < 4; ++r) sidx[r] = ei[gbase * 16 + q * 4 + r];

#pragma unroll
    for (int g = 0; g < EDGE_GPW; ++g) {
        const int e0 = (gbase + g) * 16;
        // claim output slots: one claim per edge (lanes 0..15), broadcast
        uint32_t claim = 0u;
        if (lane < 16) {
            int dv = ei[EE + e0 + lane];
            claim = atomicAdd(&cursor[dv], 1u);
        }
        uint32_t ppv[4];
#pragma unroll
        for (int r = 0; r < 4; ++r) ppv[r] = __shfl(claim, q * 4 + r);
        // x gathers (addresses ready from prefetch)
        floatx4 xa[4], xb[4];
#pragma unroll
        for (int r = 0; r < 4; ++r) {
            const float* xr = x + (size_t)sidx[r] * DD + l16 * 8;
            xa[r] = *(const floatx4*)(xr);
            xb[r] = *(const floatx4*)(xr + 4);
        }
        // prefetch next group's src indices
        int sidxn[4];
        if (g + 1 < EDGE_GPW) {
#pragma unroll
            for (int r = 0; r < 4; ++r) sidxn[r] = ei[e0 + 16 + q * 4 + r];
        }
        const float* earow = ea + (size_t)(e0 + l16) * DE + q * 8;
        floatx4 p0 = *(const floatx4*)(earow);
        floatx4 p1 = *(const floatx4*)(earow + 4);
        floatx4 p2 = *(const floatx4*)(earow + 32);
        floatx4 p3 = *(const floatx4*)(earow + 36);
        short8 af0, af1;
#pragma unroll
        for (int j = 0; j < 4; ++j) {
            af0[j]     = f2bf(p0[j]);
            af0[j + 4] = f2bf(p1[j]);
            af1[j]     = f2bf(p2[j]);
            af1[j + 4] = f2bf(p3[j]);
        }
        floatx4 acc[8];
#pragma unroll
        for (int t = 0; t < 8; ++t) {
            floatx4 z = {0.f, 0.f, 0.f, 0.f};
            z = __builtin_amdgcn_mfma_f32_16x16x32_bf16(af0, bfr[t * 2], z, 0, 0, 0);
            acc[t] = __builtin_amdgcn_mfma_f32_16x16x32_bf16(af1, bfr[t * 2 + 1], z, 0, 0, 0);
        }
#pragma unroll
        for (int r = 0; r < 4; ++r) {
            uint32_t pk[4];
#pragma unroll
            for (int tt = 0; tt < 4; ++tt) {
                float X0 = (tt < 2) ? xa[r][2 * tt]     : xb[r][2 * tt - 4];
                float X1 = (tt < 2) ? xa[r][2 * tt + 1] : xb[r][2 * tt - 3];
                float B0 = (tt < 2) ? bv0[2 * tt]       : bv1[2 * tt - 4];
                float B1 = (tt < 2) ? bv0[2 * tt + 1]   : bv1[2 * tt - 3];
                float v0 = fmaxf(acc[2 * tt][r]     + B0 + X0, 0.f);
                float v1 = fmaxf(acc[2 * tt + 1][r] + B1 + X1, 0.f);
                pk[tt] = (uint32_t)(uint16_t)f2bf(v0) | ((uint32_t)(uint16_t)f2bf(v1) << 16);
            }
            uint4 val = {pk[0], pk[1], pk[2], pk[3]};
            *(uint4*)(msg + (size_t)ppv[r] * DD + l16 * 8) = val;
        }
        if (g + 1 < EDGE_GPW) {
#pragma unroll
            for (int r = 0; r < 4; ++r) sidx[r] = sidxn[r];
        }
    }
}

// ---- segment reduce: h[n] = (1+eps)*x[n] + sum(msg rows)
#define ACC8(u) do { \
    s0 += bf2f((uint16_t)((u).x & 0xFFFFu)); s1 += bf2f((uint16_t)((u).x >> 16)); \
    s2 += bf2f((uint16_t)((u).y & 0xFFFFu)); s3 += bf2f((uint16_t)((u).y >> 16)); \
    s4 += bf2f((uint16_t)((u).z & 0xFFFFu)); s5 += bf2f((uint16_t)((u).z >> 16)); \
    s6 += bf2f((uint16_t)((u).w & 0xFFFFu)); s7 += bf2f((uint16_t)((u).w >> 16)); } while (0)

__global__ __launch_bounds__(256) void reduce_kernel(
    const uint16_t* __restrict__ msg,
    const uint32_t* __restrict__ basep,
    const float* __restrict__ x,
    const float* __restrict__ epsp,
    uint16_t* __restrict__ hbf)
{
    const int n = blockIdx.x * 4 + (threadIdx.x >> 6);
    const int lane = threadIdx.x & 63;
    const int l16 = lane & 15;
    const int q = lane >> 4;
    const uint32_t b0 = basep[n];
    const uint32_t d = basep[n + 1] - b0;
    const uint4* bp = (const uint4*)((const uint32_t*)msg + (size_t)b0 * 64) + lane;
    float s0 = 0.f, s1 = 0.f, s2 = 0.f, s3 = 0.f;
    float s4 = 0.f, s5 = 0.f, s6 = 0.f, s7 = 0.f;
    const uint32_t nb = d >> 2;
    const uint32_t rem = d & 3u;
    uint32_t i = 0;
    for (; i + 2 <= nb; i += 2) {
        uint4 a = bp[(size_t)i * 64];
        uint4 b = bp[(size_t)(i + 1) * 64];
        ACC8(a); ACC8(b);
    }
    if (i < nb) { uint4 a = bp[(size_t)i * 64]; ACC8(a); }
    if ((uint32_t)q < rem) { uint4 a = bp[(size_t)nb * 64]; ACC8(a); }
    s0 += __shfl_xor(s0, 16); s0 += __shfl_xor(s0, 32);
    s1 += __shfl_xor(s1, 16); s1 += __shfl_xor(s1, 32);
    s2 += __shfl_xor(s2, 16); s2 += __shfl_xor(s2, 32);
    s3 += __shfl_xor(s3, 16); s3 += __shfl_xor(s3, 32);
    s4 += __shfl_xor(s4, 16); s4 += __shfl_xor(s4, 32);
    s5 += __shfl_xor(s5, 16); s5 += __shfl_xor(s5, 32);
    s6 += __shfl_xor(s6, 16); s6 += __shfl_xor(s6, 32);
    s7 += __shfl_xor(s7, 16); s7 += __shfl_xor(s7, 32);
    const float c1 = 1.0f + epsp[0];
    const float2 xv = *(const float2*)(x + (size_t)n * DD + (l16 * 4 + q) * 2);
    float a0 = (q == 0) ? s0 : (q == 1) ? s2 : (q == 2) ? s4 : s6;
    float a1 = (q == 0) ? s1 : (q == 1) ? s3 : (q == 2) ? s5 : s7;
    uint32_t pk = (uint32_t)(uint16_t)f2bf(c1 * xv.x + a0) |
                  ((uint32_t)(uint16_t)f2bf(c1 * xv.y + a1) << 16);
    ((uint32_t*)hbf)[(size_t)n * 64 + l16 * 4 + q] = pk;
}

// ---- GEMM1: t1[N,256](bf16) = h @ W1^T + b1 (natural order via efeat W1),
// fused BN1 stats. Two passes of 8 nt; vectorized 16B stores; q-shfl stats.
__global__ __launch_bounds__(256) void gemm1_kernel(
    const uint16_t* __restrict__ hbf,
    const short* __restrict__ w1swz,
    const float* __restrict__ b1,
    uint16_t* __restrict__ t1,
    float* __restrict__ gsum,
    float* __restrict__ gsq)
{
    __shared__ float ls[H1];
    __shared__ float ls2[H1];
    const int tid = threadIdx.x;
    ls[tid] = 0.f; ls2[tid] = 0.f;
    __syncthreads();

    const int wave = tid >> 6;
    const int lane = tid & 63;
    const int l16 = lane & 15;
    const int q = lane >> 4;
    const short8* wp = (const short8*)w1swz;

    const int grp = blockIdx.x * 4 + wave;
    if (grp < NGRP) {
        const int n0 = grp * 16;
        const uint16_t* hr = hbf + (size_t)(n0 + l16) * DD + q * 8;
        short8 af[4];
#pragma unroll
        for (int kc = 0; kc < 4; ++kc) af[kc] = *(const short8*)(hr + kc * 32);
#pragma unroll
        for (int pass = 0; pass < 2; ++pass) {
            floatx4 a8[8];
#pragma unroll
            for (int t = 0; t < 8; ++t) a8[t] = (floatx4){0.f, 0.f, 0.f, 0.f};
#pragma unroll
            for (int t = 0; t < 8; ++t) {
                const int nt = pass * 8 + t;
#pragma unroll
                for (int kc = 0; kc < 4; ++kc)
                    a8[t] = __builtin_amdgcn_mfma_f32_16x16x32_bf16(
                        af[kc], wp[(nt * 4 + kc) * 64 + lane], a8[t], 0, 0, 0);
            }
            floatx4 bva = *(const floatx4*)(b1 + l16 * 16 + pass * 8);
            floatx4 bvb = *(const floatx4*)(b1 + l16 * 16 + pass * 8 + 4);
            float sa[8], s2a[8];
#pragma unroll
            for (int t = 0; t < 8; ++t) { sa[t] = 0.f; s2a[t] = 0.f; }
#pragma unroll
            for (int r = 0; r < 4; ++r) {
                uint32_t pk[4];
#pragma unroll
                for (int t2 = 0; t2 < 4; ++t2) {
                    float B0 = (t2 < 2) ? bva[2 * t2]     : bvb[2 * t2 - 4];
                    float B1 = (t2 < 2) ? bva[2 * t2 + 1] : bvb[2 * t2 - 3];
                    float v0 = a8[2 * t2][r] + B0;
                    float v1 = a8[2 * t2 + 1][r] + B1;
                    sa[2 * t2] += v0; s2a[2 * t2] += v0 * v0;
                    sa[2 * t2 + 1] += v1; s2a[2 * t2 + 1] += v1 * v1;
                    pk[t2] = (uint32_t)(uint16_t)f2bf(v0) |
                             ((uint32_t)(uint16_t)f2bf(v1) << 16);
                }
                *(uint4*)(t1 + (size_t)(n0 + q * 4 + r) * H1 + l16 * 16 + pass * 8) =
                    (uint4){pk[0], pk[1], pk[2], pk[3]};
            }
#pragma unroll
            for (int t = 0; t < 8; ++t) {
                float s = sa[t], s2 = s2a[t];
                s += __shfl_xor(s, 16);  s += __shfl_xor(s, 32);
                s2 += __shfl_xor(s2, 16); s2 += __shfl_xor(s2, 32);
                if (q == 0) {
                    atomicAdd(&ls[l16 * 16 + pass * 8 + t], s);
                    atomicAdd(&ls2[l16 * 16 + pass * 8 + t], s2);
                }
            }
        }
    }
    __syncthreads();
    atomicAdd(&gsum[tid], ls[tid]);
    atomicAdd(&gsq[tid], ls2[tid]);
}

// ---- GEMM2: h2[N,128](bf16) = relu(t1*scale1+shift1) @ W2^T + b2 (natural
// order via efeat W2), BN2 stats. Vectorized stores; q-shfl stats.
__global__ __launch_bounds__(256) void gemm2_kernel(
    const uint16_t* __restrict__ t1,
    const float* __restrict__ scale1,
    const float* __restrict__ shift1,
    const short* __restrict__ w2swz,
    const float* __restrict__ b2,
    uint16_t* __restrict__ h2,
    float* __restrict__ gsum,
    float* __restrict__ gsq)
{
    __shared__ float ls[DD];
    __shared__ float ls2[DD];
    const int tid = threadIdx.x;
    if (tid < DD) { ls[tid] = 0.f; ls2[tid] = 0.f; }
    __syncthreads();

    const int wave = tid >> 6;
    const int lane = tid & 63;
    const int l16 = lane & 15;
    const int q = lane >> 4;
    const short8* wp = (const short8*)w2swz;

    const int grp = blockIdx.x * 4 + wave;
    if (grp < NGRP) {
        const int n0 = grp * 16;
        const uint16_t* tr = t1 + (size_t)(n0 + l16) * H1 + q * 8;
        floatx4 acc[8];
#pragma unroll
        for (int nt = 0; nt < 8; ++nt) acc[nt] = (floatx4){0.f, 0.f, 0.f, 0.f};
#pragma unroll
        for (int kc = 0; kc < 8; ++kc) {
            short8 tv = *(const short8*)(tr + kc * 32);
            const int kb = kc * 32 + q * 8;
            short8 af;
#pragma unroll
            for (int j = 0; j < 8; ++j) {
                float u = bf2f((uint16_t)tv[j]) * scale1[kb + j] + shift1[kb + j];
                af[j] = f2bf(fmaxf(u, 0.f));
            }
#pragma unroll
            for (int nt = 0; nt < 8; ++nt)
                acc[nt] = __builtin_amdgcn_mfma_f32_16x16x32_bf16(
                    af, wp[(nt * 8 + kc) * 64 + lane], acc[nt], 0, 0, 0);
        }
        floatx4 bva = *(const floatx4*)(b2 + l16 * 8);
        floatx4 bvb = *(const floatx4*)(b2 + l16 * 8 + 4);
        float sa[8], s2a[8];
#pragma unroll
        for (int t = 0; t < 8; ++t) { sa[t] = 0.f; s2a[t] = 0.f; }
#pragma unroll
        for (int r = 0; r < 4; ++r) {
            uint32_t pk[4];
#pragma unroll
            for (int t2 = 0; t2 < 4; ++t2) {
                float B0 = (t2 < 2) ? bva[2 * t2]     : bvb[2 * t2 - 4];
                float B1 = (t2 < 2) ? bva[2 * t2 + 1] : bvb[2 * t2 - 3];
                float v0 = acc[2 * t2][r] + B0;
                float v1 = acc[2 * t2 + 1][r] + B1;
                sa[2 * t2] += v0; s2a[2 * t2] += v0 * v0;
                sa[2 * t2 + 1] += v1; s2a[2 * t2 + 1] += v1 * v1;
                pk[t2] = (uint32_t)(uint16_t)f2bf(v0) |
                         ((uint32_t)(uint16_t)f2bf(v1) << 16);
            }
            *(uint4*)(h2 + (size_t)(n0 + q * 4 + r) * DD + l16 * 8) =
                (uint4){pk[0], pk[1], pk[2], pk[3]};
        }
#pragma unroll
        for (int t = 0; t < 8; ++t) {
            float s = sa[t], s2 = s2a[t];
            s += __shfl_xor(s, 16);  s += __shfl_xor(s, 32);
            s2 += __shfl_xor(s2, 16); s2 += __shfl_xor(s2, 32);
            if (q == 0) {
                atomicAdd(&ls[l16 * 8 + t], s);
                atomicAdd(&ls2[l16 * 8 + t], s2);
            }
        }
    }
    __syncthreads();
    if (tid < DD) {
        atomicAdd(&gsum[tid], ls[tid]);
        atomicAdd(&gsq[tid], ls2[tid]);
    }
}

__global__ void finalize_kernel(const float* __restrict__ ssum,
                                const float* __restrict__ ssumsq,
                                const float* __restrict__ gamma,
                                const float* __restrict__ beta,
                                float* __restrict__ scale,
                                float* __restrict__ shift, int C) {
    int c = threadIdx.x;
    if (c >= C) return;
    float mu = ssum[c] * (1.0f / NN);
    float var = ssumsq[c] * (1.0f / NN) - mu * mu;
    float rs = rsqrtf(var + 1e-5f);
    float sc = gamma[c] * rs;
    scale[c] = sc;
    shift[c] = beta[c] - mu * sc;
}

__global__ __launch_bounds__(256) void out_kernel(const uint16_t* __restrict__ h2,
                                                  const float* __restrict__ scale2,
                                                  const float* __restrict__ shift2,
                                                  float* __restrict__ out) {
    int idx = blockIdx.x * 256 + threadIdx.x;
    int base = idx * 8;   // NN*DD = 6.4M elems, 800000 threads
    int c = base & (DD - 1);
    uint4 pk = *(const uint4*)(h2 + base);
    const uint32_t u[4] = {pk.x, pk.y, pk.z, pk.w};
    floatx4 o0, o1;
#pragma unroll
    for (int j = 0; j < 4; ++j) {
        float vlo = bf2f((uint16_t)(u[j] & 0xFFFFu));
        float vhi = bf2f((uint16_t)(u[j] >> 16));
        int cc = c + j * 2;
        float a = fmaxf(vlo * scale2[cc] + shift2[cc], 0.f);
        float b = fmaxf(vhi * scale2[cc + 1] + shift2[cc + 1], 0.f);
        if (j < 2) { o0[j * 2] = a; o0[j * 2 + 1] = b; }
        else       { o1[(j - 2) * 2] = a; o1[(j - 2) * 2 + 1] = b; }
    }
    *(floatx4*)(out + base) = o0;
    *(floatx4*)(out + base + 4) = o1;
}

extern "C" void kernel_launch(void* const* d_in, const int* in_sizes, int n_in,
                              void* d_out, int out_size, void* d_ws, size_t ws_size,
                              hipStream_t stream) {
    const float* x     = (const float*)d_in[0];
    const int*   ei    = (const int*)d_in[1];
    const float* ea    = (const float*)d_in[2];
    const float* We    = (const float*)d_in[3];
    const float* be    = (const float*)d_in[4];
    const float* W1    = (const float*)d_in[5];
    const float* b1    = (const float*)d_in[6];
    const float* g1    = (const float*)d_in[7];
    const float* beta1 = (const float*)d_in[8];
    const float* W2    = (const float*)d_in[9];
    const float* b2    = (const float*)d_in[10];
    const float* g2    = (const float*)d_in[11];
    const float* beta2 = (const float*)d_in[12];
    const float* epsp  = (const float*)d_in[13];

    float* ws      = (float*)d_ws;
    float* gsum1   = ws + 0;
    float* gsq1    = ws + 256;
    float* gsum2   = ws + 512;
    float* gsq2    = ws + 640;
    float* scale1  = ws + 768;
    float* shift1  = ws + 1024;
    float* scale2  = ws + 1280;
    float* shift2  = ws + 1408;
    uint32_t* deg     = (uint32_t*)(ws + 1536);   // 50176
    uint32_t* basep   = deg + 50176;              // 50432 (NN+1 used)
    uint32_t* cursor  = basep + 50432;            // 50176
    uint32_t* partial = cursor + 50176;           // 256
    uint16_t* hbf     = (uint16_t*)(partial + 256);  // NN*DD bf16
    uint16_t* msg     = hbf + (size_t)NN * DD;    // EE*DD bf16 (204.8 MB)
    uint16_t* t1      = msg;                      // alias: msg dead after reduce
    uint16_t* h2      = t1 + (size_t)NN * H1;
    short*    wswz    = (short*)(msg + (size_t)EE * DD);  // 73728
    short*    weswz   = wswz;
    short*    w1swz   = wswz + 8192;
    short*    w2swz   = wswz + 40960;

    // zero stats (1536 f32) + deg (50176 u32), contiguous
    hipMemsetAsync(ws, 0, (1536 + 50176) * sizeof(uint32_t), stream);

    swz_all_kernel<<<dim3(288), 256, 0, stream>>>(We, W1, W2, wswz);
    count_kernel<<<dim3(3125), 256, 0, stream>>>(ei, deg);
    scan1_kernel<<<dim3(196), 256, 0, stream>>>(deg, partial);
    scan2_kernel<<<dim3(1), 256, 0, stream>>>(partial);
    scan3_kernel<<<dim3(196), 256, 0, stream>>>(deg, partial, basep, cursor);

    edge_kernel<<<dim3(2500), 256, 0, stream>>>(x, ei, ea, weswz, be, cursor, msg);
    reduce_kernel<<<dim3(12500), 256, 0, stream>>>(msg, basep, x, epsp, hbf);

    gemm1_kernel<<<dim3(782), 256, 0, stream>>>(hbf, w1swz, b1, t1, gsum1, gsq1);
    finalize_kernel<<<dim3(1), 256, 0, stream>>>(gsum1, gsq1, g1, beta1, scale1, shift1, H1);

    gemm2_kernel<<<dim3(782), 256, 0, stream>>>(t1, scale1, shift1, w2swz, b2, h2, gsum2, gsq2);
    finalize_kernel<<<dim3(1), 128, 0, stream>>>(gsum2, gsq2, g2, beta2, scale2, shift2, DD);

    out_kernel<<<dim3(3125), 256, 0, stream>>>(h2, scale2, shift2, (float*)d_out);
}